// Round 19
// baseline (208.830 us; speedup 1.0000x reference)
//
#include <hip/hip_runtime.h>
#include <hip/hip_bf16.h>
#include <math.h>

#define NPTS 500000
#define M_ASSIGN 400000
#define WPR 15625   // 500000/32 words per bitmap row
#define NWIN 31250  // NPTS/16 windows of 16 points (exact)
#define NBIAS 489   // ceil(500000/1024) blocks for bias path

// workspace layout (float units)
constexpr int    OFF_ACC      = 0;        // [0]=nll_sum [1]=valid_cnt [2]=l1_sum [3]=cos_sum [4]=mask_sum
constexpr int    OFF_SUM      = 64;       // 64 BN sums (of raw h, no b1)
constexpr int    OFF_SQ       = 128;      // 64 BN sumsq
constexpr int    OFF_BITMAP   = 320;      // 2,000,000 uint32
constexpr int    OFF_SEGPRED  = 2000320;  // 500,000 int
constexpr int    OFF_PROBS    = 2500448;  // probs TRANSPOSED: [20][NPTS] bf16 (10M u16)
constexpr size_t OFF_H        = 12500448; // u8 h: NWIN*4*64 u32 (32MB)
constexpr size_t OFF_FRAGS    = 28500448; // 12 frags x 64 lanes x 16B

typedef __attribute__((ext_vector_type(8))) short short8v;
typedef __attribute__((ext_vector_type(4))) float f32x4;

__device__ inline unsigned bf16rne(float x) {
  unsigned u = __float_as_uint(x);
  return (u + 0x7fffu + ((u >> 16) & 1u)) >> 16;
}
__device__ inline unsigned pk2(float lo, float hi) {
  return bf16rne(lo) | (bf16rne(hi) << 16);
}
// h quantizer: q = clamp(rne(h*16)+128) ; h = q/16 - 8
__device__ inline unsigned q8(float v) {
  int q = (int)rintf(fmaf(v, 16.f, 128.f));
  q = q < 0 ? 0 : (q > 255 ? 255 : q);
  return (unsigned)q;
}

// ---------------------------------------------------------------------------
// K0: build the 12 packed-bf16 B fragments once (12KB)
// ---------------------------------------------------------------------------
__global__ void prep_kernel(const float* __restrict__ w1,
                            const float* __restrict__ seg_w,
                            float* __restrict__ ws)
{
  uint4* fr = (uint4*)(ws + OFF_FRAGS);
  for (int slot = threadIdx.x; slot < 768; slot += 256) {
    const int f = slot >> 6, l = slot & 63;
    const int col = l & 15, kg = l >> 4;
    const int t = f >> 1, ks = f & 1;
    union { uint4 q; unsigned short u[8]; } bu;
    #pragma unroll
    for (int i = 0; i < 8; ++i) {
      const int k = ks * 32 + kg * 8 + i;
      float v;
      if (t < 4)       v = w1[k * 64 + t * 16 + col];
      else if (t == 4) v = seg_w[k * 20 + col];
      else             v = (col < 4) ? seg_w[k * 20 + 16 + col] : 0.f;
      bu.u[i] = (unsigned short)bf16rne(v);
    }
    fr[slot] = bu.q;
  }
}

// ---------------------------------------------------------------------------
// K1 (MFMA, barrier-free, depth-2 pipeline, assign fused at head):
// [h | seg logits] = feat@[w1|seg_w]; h u8; probs bf16 stored CLASS-MAJOR
// ([20][NPTS]) so score's per-proposal gather stays inside one 1MB plane.
// ---------------------------------------------------------------------------
__global__ __launch_bounds__(256) void gemm_kernel(
    const float* __restrict__ feat, const float* __restrict__ seg_b,
    const int* __restrict__ segment, const int* __restrict__ prop_ids,
    const int* __restrict__ point_ids, float* __restrict__ ws)
{
  float* acc   = ws + OFF_ACC;
  int*   segp  = (int*)(ws + OFF_SEGPRED);
  unsigned short* probs16 = (unsigned short*)(ws + OFF_PROBS);
  unsigned* h8 = (unsigned*)(ws + OFF_H);
  unsigned* bitmap = (unsigned*)(ws + OFF_BITMAP);

  const int tid  = threadIdx.x;
  const int lane = tid & 63;
  const int col  = lane & 15;
  const int kg   = lane >> 4;
  const int wslot0  = blockIdx.x * 4 + (tid >> 6);
  const int wstride = gridDim.x * 4;

  // ---- fused assign: scatter-or the dedupe bitmap (overlaps with frag loads)
  for (int i = blockIdx.x * 256 + tid; i < M_ASSIGN; i += 262144) {
    const int p = prop_ids[i];
    const int n = point_ids[i];
    atomicOr(&bitmap[p * WPR + (n >> 5)], 1u << (n & 31));
  }

  // ---- load prebuilt B fragments (12 coalesced 16B loads) ----
  const uint4* fr = (const uint4*)(ws + OFF_FRAGS);
  auto ldf = [&](int f) -> short8v {
    union { uint4 q; short8v v; } u;
    u.q = fr[f * 64 + lane];
    return u.v;
  };
  const short8v B00 = ldf(0),  B01 = ldf(1);
  const short8v B10 = ldf(2),  B11 = ldf(3);
  const short8v B20 = ldf(4),  B21 = ldf(5);
  const short8v B30 = ldf(6),  B31 = ldf(7);
  const short8v B40 = ldf(8),  B41 = ldf(9);
  const short8v B50 = ldf(10), B51 = ldf(11);

  const float sb4 = seg_b[col];
  const float sb5 = (col < 4) ? seg_b[16 + col] : 0.f;

  float bnsum[4] = {0.f, 0.f, 0.f, 0.f};
  float bnsq[4]  = {0.f, 0.f, 0.f, 0.f};
  float nll_acc = 0.f, vld_acc = 0.f;

  auto do_window = [&](int W, const short8v& A0v, const short8v& A1v) {
    f32x4 ac0 = {0.f,0.f,0.f,0.f}, ac1 = ac0, ac2 = ac0, ac3 = ac0;
    f32x4 ac4 = {sb4, sb4, sb4, sb4};
    f32x4 ac5 = {sb5, sb5, sb5, sb5};
    ac0 = __builtin_amdgcn_mfma_f32_16x16x32_bf16(A0v, B00, ac0, 0, 0, 0);
    ac0 = __builtin_amdgcn_mfma_f32_16x16x32_bf16(A1v, B01, ac0, 0, 0, 0);
    ac1 = __builtin_amdgcn_mfma_f32_16x16x32_bf16(A0v, B10, ac1, 0, 0, 0);
    ac1 = __builtin_amdgcn_mfma_f32_16x16x32_bf16(A1v, B11, ac1, 0, 0, 0);
    ac2 = __builtin_amdgcn_mfma_f32_16x16x32_bf16(A0v, B20, ac2, 0, 0, 0);
    ac2 = __builtin_amdgcn_mfma_f32_16x16x32_bf16(A1v, B21, ac2, 0, 0, 0);
    ac3 = __builtin_amdgcn_mfma_f32_16x16x32_bf16(A0v, B30, ac3, 0, 0, 0);
    ac3 = __builtin_amdgcn_mfma_f32_16x16x32_bf16(A1v, B31, ac3, 0, 0, 0);
    ac4 = __builtin_amdgcn_mfma_f32_16x16x32_bf16(A0v, B40, ac4, 0, 0, 0);
    ac4 = __builtin_amdgcn_mfma_f32_16x16x32_bf16(A1v, B41, ac4, 0, 0, 0);
    ac5 = __builtin_amdgcn_mfma_f32_16x16x32_bf16(A0v, B50, ac5, 0, 0, 0);
    ac5 = __builtin_amdgcn_mfma_f32_16x16x32_bf16(A1v, B51, ac5, 0, 0, 0);

    #pragma unroll
    for (int r = 0; r < 4; ++r) {
      bnsum[0] += ac0[r]; bnsq[0] += ac0[r] * ac0[r];
      bnsum[1] += ac1[r]; bnsq[1] += ac1[r] * ac1[r];
      bnsum[2] += ac2[r]; bnsq[2] += ac2[r] * ac2[r];
      bnsum[3] += ac3[r]; bnsq[3] += ac3[r] * ac3[r];
      h8[(size_t)(W * 4 + r) * 64 + lane] =
          q8(ac0[r]) | (q8(ac1[r]) << 8) | (q8(ac2[r]) << 16) | (q8(ac3[r]) << 24);

      const int p = W * 16 + kg * 4 + r;
      const int seg = segment[p];
      const float l4 = ac4[r];
      const float l5 = ac5[r];
      float mv; int mi;
      if (col < 4 && l5 > l4) { mv = l5; mi = 16 + col; }
      else                    { mv = l4; mi = col; }
      #pragma unroll
      for (int msk = 1; msk < 16; msk <<= 1) {
        const float om = __shfl_xor(mv, msk);
        const int   oi = __shfl_xor(mi, msk);
        if (om > mv || (om == mv && oi < mi)) { mv = om; mi = oi; }
      }
      const float e4 = __expf(l4 - mv);
      const float e5 = (col < 4) ? __expf(l5 - mv) : 0.f;
      const int sidx = seg < 0 ? 0 : (seg > 19 ? 19 : seg);
      float sp = e4 + e5;
      float lv = (col == sidx ? l4 : 0.f) + ((col < 4 && (16 + col) == sidx) ? l5 : 0.f);
      #pragma unroll
      for (int msk = 1; msk < 16; msk <<= 1) {
        sp += __shfl_xor(sp, msk);
        lv += __shfl_xor(lv, msk);
      }
      const float inv = 1.f / sp;
      // CLASS-MAJOR probs: plane col, position p
      probs16[(size_t)col * NPTS + p] = (unsigned short)bf16rne(e4 * inv);
      if (col < 4) probs16[(size_t)(16 + col) * NPTS + p] = (unsigned short)bf16rne(e5 * inv);
      if (col == 0) {
        segp[p] = mi;
        const bool svalid = (seg != -1);
        nll_acc += svalid ? (mv + __logf(sp) - lv) : 0.f;
        vld_acc += svalid ? 1.f : 0.f;
      }
    }
  };

  auto loadA = [&](int W, f32x4& c0, f32x4& c1, f32x4& c2, f32x4& c3) {
    c0 = (f32x4){0.f,0.f,0.f,0.f}; c1 = c0; c2 = c0; c3 = c0;
    if (W < NWIN) {
      const float* fp = feat + (size_t)(W * 16 + col) * 64 + kg * 8;
      c0 = *(const f32x4*)(fp);
      c1 = *(const f32x4*)(fp + 4);
      c2 = *(const f32x4*)(fp + 32);
      c3 = *(const f32x4*)(fp + 36);
    }
  };
  auto cvtA = [&](const f32x4& c0, const f32x4& c1, const f32x4& c2, const f32x4& c3,
                  short8v& A0v, short8v& A1v) {
    union { short8v v; unsigned u[4]; } A0, A1;
    A0.u[0] = pk2(c0[0], c0[1]); A0.u[1] = pk2(c0[2], c0[3]);
    A0.u[2] = pk2(c1[0], c1[1]); A0.u[3] = pk2(c1[2], c1[3]);
    A1.u[0] = pk2(c2[0], c2[1]); A1.u[1] = pk2(c2[2], c2[3]);
    A1.u[2] = pk2(c3[0], c3[1]); A1.u[3] = pk2(c3[2], c3[3]);
    A0v = A0.v; A1v = A1.v;
  };

  // ---- depth-2 software pipeline ----
  f32x4 pa0, pa1, pa2, pa3, pb0, pb1, pb2, pb3;
  loadA(wslot0,            pa0, pa1, pa2, pa3);
  loadA(wslot0 + wstride,  pb0, pb1, pb2, pb3);

  for (int W = wslot0; W < NWIN; W += 2 * wstride) {
    {
      short8v A0v, A1v;
      cvtA(pa0, pa1, pa2, pa3, A0v, A1v);
      loadA(W + 2 * wstride, pa0, pa1, pa2, pa3);
      do_window(W, A0v, A1v);
    }
    const int W2 = W + wstride;
    if (W2 < NWIN) {
      short8v A0v, A1v;
      cvtA(pb0, pb1, pb2, pb3, A0v, A1v);
      loadA(W2 + 2 * wstride, pb0, pb1, pb2, pb3);
      do_window(W2, A0v, A1v);
    }
  }

  // ---- BN reduce ----
  #pragma unroll
  for (int t = 0; t < 4; ++t) {
    float s = bnsum[t], q = bnsq[t];
    s += __shfl_down(s, 32); s += __shfl_down(s, 16);
    q += __shfl_down(q, 32); q += __shfl_down(q, 16);
    if (lane < 16) {
      atomicAdd(&ws[OFF_SUM + t * 16 + lane], s);
      atomicAdd(&ws[OFF_SQ  + t * 16 + lane], q);
    }
  }
  float s = nll_acc, v = vld_acc;
  #pragma unroll
  for (int o = 32; o > 0; o >>= 1) { s += __shfl_down(s, o); v += __shfl_down(v, o); }
  if (lane == 0) { atomicAdd(&acc[0], s); atomicAdd(&acc[1], v); }
}

// ---------------------------------------------------------------------------
// K2 (merged): blocks [0,NBIAS) = bias-loss path (1024 thr, 1 point/thread);
// blocks [NBIAS, NBIAS+128) = per-proposal score path (class-major plane).
// ---------------------------------------------------------------------------
__global__ __launch_bounds__(1024) void biasscore_kernel(
    const float* __restrict__ coord, const float* __restrict__ cent,
    const float* __restrict__ gamma, const float* __restrict__ beta,
    const float* __restrict__ w2, const float* __restrict__ b2,
    const int* __restrict__ instance, const int* __restrict__ prop_ids,
    const int* __restrict__ point_ids, float* __restrict__ ws,
    float* __restrict__ out)
{
  const int tid = threadIdx.x;

  if (blockIdx.x < NBIAS) {
    // ================= bias-loss path =================
    __shared__ float scs[64], shs[64];
    __shared__ float r0[16], r1[16], r2[16];
    float* acc = ws + OFF_ACC;
    const unsigned* h8 = (const unsigned*)(ws + OFF_H);

    if (tid < 64) {
      const float mu  = ws[OFF_SUM + tid] * (1.f / NPTS);
      const float var = ws[OFF_SQ  + tid] * (1.f / NPTS) - mu * mu;
      const float sc = gamma[tid] * rsqrtf(var + 0.001f);
      scs[tid] = sc;
      shs[tid] = beta[tid] - mu * sc;   // b1 cancels through BN
    }
    __syncthreads();

    const int n = blockIdx.x * 1024 + tid;
    float l1v = 0.f, cosv = 0.f, mk = 0.f;
    if (n < NPTS) {
      const int W = n >> 4, q = n & 15, kg = (q >> 2) & 3, r = q & 3;
      const uint4* hp = (const uint4*)(h8 + ((size_t)(W * 4 + r) * 64 + kg * 16));
      uint4 u[4];
      #pragma unroll
      for (int i = 0; i < 4; ++i) u[i] = hp[i];

      float bx = b2[0], by = b2[1], bz = b2[2];
      #pragma unroll
      for (int i = 0; i < 4; ++i) {
        const unsigned uu[4] = {u[i].x, u[i].y, u[i].z, u[i].w};
        #pragma unroll
        for (int j = 0; j < 4; ++j) {
          const int cgi = i * 4 + j;
          const unsigned w = uu[j];
          #pragma unroll
          for (int b = 0; b < 4; ++b) {
            const int ch = cgi + 16 * b;
            const float h = (float)(int)((w >> (8 * b)) & 255u) * 0.0625f - 8.f;
            const float hr = fmaxf(fmaf(h, scs[ch], shs[ch]), 0.f);
            bx = fmaf(hr, w2[ch * 3 + 0], bx);
            by = fmaf(hr, w2[ch * 3 + 1], by);
            bz = fmaf(hr, w2[ch * 3 + 2], bz);
          }
        }
      }
      const float cx = coord[(size_t)n*3+0], cy = coord[(size_t)n*3+1], cz = coord[(size_t)n*3+2];
      const float ex = cent[(size_t)n*3+0],  ey = cent[(size_t)n*3+1],  ez = cent[(size_t)n*3+2];
      const float gx = ex - cx, gy = ey - cy, gz = ez - cz;
      const float dx = bx - gx, dy = by - gy, dz = bz - gz;
      const float l1 = fabsf(dx) + fabsf(dy) + fabsf(dz);
      const float npn = sqrtf(bx*bx + by*by + bz*bz) + 1e-8f;
      const float ngn = sqrtf(gx*gx + gy*gy + gz*gz) + 1e-8f;
      const float cv = -(bx*gx + by*gy + bz*gz) / (npn * ngn);
      mk = (instance[n] != -1) ? 1.f : 0.f;
      l1v = l1 * mk;
      cosv = cv * mk;
    }
    #pragma unroll
    for (int o = 32; o > 0; o >>= 1) {
      l1v  += __shfl_down(l1v, o);
      cosv += __shfl_down(cosv, o);
      mk   += __shfl_down(mk, o);
    }
    if ((tid & 63) == 0) { r0[tid>>6] = l1v; r1[tid>>6] = cosv; r2[tid>>6] = mk; }
    __syncthreads();
    if (tid == 0) {
      float a = 0.f, b = 0.f, c = 0.f;
      #pragma unroll
      for (int i = 0; i < 16; ++i) { a += r0[i]; b += r1[i]; c += r2[i]; }
      atomicAdd(&acc[2], a);
      atomicAdd(&acc[3], b);
      atomicAdd(&acc[4], c);
    }
  } else {
    // ================= score path =================
    const unsigned* bitmap = (const unsigned*)(ws + OFF_BITMAP);
    const unsigned short* probs16 = (const unsigned short*)(ws + OFF_PROBS);
    const int* segp = (const int*)(ws + OFF_SEGPRED);
    __shared__ float rs[16];
    __shared__ int rc[16];
    const int p = blockIdx.x - NBIAS;

    int lo = 0, hi = M_ASSIGN;
    while (lo < hi) { const int mid = (lo + hi) >> 1; if (prop_ids[mid] < p) lo = mid + 1; else hi = mid; }
    if (lo > M_ASSIGN - 1) lo = M_ASSIGN - 1;
    const int cp = segp[point_ids[lo]];
    const unsigned short* plane = probs16 + (size_t)cp * NPTS;

    float s = 0.f; int cnt = 0;
    for (int w = tid; w < WPR; w += 1024) {
      unsigned bits = bitmap[p * WPR + w];
      cnt += __popc(bits);
      while (bits) {
        const int b = __ffs(bits) - 1;
        bits &= bits - 1;
        const int n = (w << 5) + b;
        s += __uint_as_float((unsigned)plane[n] << 16);
      }
    }
    #pragma unroll
    for (int o = 32; o > 0; o >>= 1) { s += __shfl_down(s, o); cnt += __shfl_down(cnt, o); }
    if ((tid & 63) == 0) { rs[tid >> 6] = s; rc[tid >> 6] = cnt; }
    __syncthreads();
    if (tid == 0) {
      float st = 0.f; int ct = 0;
      #pragma unroll
      for (int i = 0; i < 16; ++i) { st += rs[i]; ct += rc[i]; }
      const bool mk = ct > 100;
      out[1 + p]   = mk ? st / (float)(ct > 1 ? ct : 1) : 0.f;
      out[129 + p] = mk ? 1.f : 0.f;
      if (p == 0) {
        const float segl = ws[0] / fmaxf(ws[1], 1.f);
        const float d = ws[4] + 1e-8f;
        out[0] = segl + ws[2] / d + ws[3] / d;
      }
    }
  }
}

extern "C" void kernel_launch(void* const* d_in, const int* in_sizes, int n_in,
                              void* d_out, int out_size, void* d_ws, size_t ws_size,
                              hipStream_t stream) {
  const float* feat    = (const float*)d_in[0];
  const float* coord   = (const float*)d_in[1];
  const float* cent    = (const float*)d_in[2];
  const float* w1      = (const float*)d_in[3];
  // d_in[4] = b1 : cancels through BN, unused
  const float* gamma   = (const float*)d_in[5];
  const float* beta    = (const float*)d_in[6];
  const float* w2      = (const float*)d_in[7];
  const float* b2      = (const float*)d_in[8];
  const float* seg_w   = (const float*)d_in[9];
  const float* seg_b   = (const float*)d_in[10];
  const int* segment   = (const int*)d_in[11];
  const int* instance  = (const int*)d_in[12];
  const int* prop_ids  = (const int*)d_in[13];
  const int* point_ids = (const int*)d_in[14];
  float* out = (float*)d_out;
  float* ws  = (float*)d_ws;

  // zero accumulators + BN sums + bitmap
  hipMemsetAsync(d_ws, 0, (size_t)(OFF_BITMAP + 2000000) * sizeof(float), stream);

  prep_kernel<<<1, 256, 0, stream>>>(w1, seg_w, ws);
  gemm_kernel<<<1024, 256, 0, stream>>>(feat, seg_b, segment, prop_ids, point_ids, ws);
  biasscore_kernel<<<NBIAS + 128, 1024, 0, stream>>>(coord, cent, gamma, beta, w2, b2,
                                                     instance, prop_ids, point_ids, ws, out);
}

// Round 20
// 202.839 us; speedup vs baseline: 1.0295x; 1.0295x over previous
//
#include <hip/hip_runtime.h>
#include <hip/hip_bf16.h>
#include <math.h>

#define NPTS 500000
#define M_ASSIGN 400000
#define WPR 15625   // 500000/32 words per bitmap row
#define NWIN 31250  // NPTS/16 windows of 16 points (exact)
#define NBIAS 489   // ceil(500000/1024) blocks for bias path
#define NZERO 2000320  // floats to zero: ACC..SUM..SQ..BITMAP

// workspace layout (float units)
constexpr int    OFF_ACC      = 0;        // [0]=nll_sum [1]=valid_cnt [2]=l1_sum [3]=cos_sum [4]=mask_sum
constexpr int    OFF_SUM      = 64;       // 64 BN sums (of raw h, no b1)
constexpr int    OFF_SQ       = 128;      // 64 BN sumsq
constexpr int    OFF_BITMAP   = 320;      // 2,000,000 uint32
constexpr int    OFF_SEGPRED  = 2000320;  // 500,000 int
constexpr int    OFF_PROBS    = 2500448;  // 500000*20 bf16 (point-major)
constexpr size_t OFF_H        = 12500448; // u8 h: NWIN*4*64 u32 (32MB)
constexpr size_t OFF_FRAGS    = 28500448; // 12 frags x 64 lanes x 16B

typedef __attribute__((ext_vector_type(8))) short short8v;
typedef __attribute__((ext_vector_type(4))) float f32x4;

__device__ inline unsigned bf16rne(float x) {
  unsigned u = __float_as_uint(x);
  return (u + 0x7fffu + ((u >> 16) & 1u)) >> 16;
}
__device__ inline unsigned pk2(float lo, float hi) {
  return bf16rne(lo) | (bf16rne(hi) << 16);
}
// h quantizer: q = clamp(rne(h*16)+128) ; h = q/16 - 8
__device__ inline unsigned q8(float v) {
  int q = (int)rintf(fmaf(v, 16.f, 128.f));
  q = q < 0 ? 0 : (q > 255 ? 255 : q);
  return (unsigned)q;
}

// ---------------------------------------------------------------------------
// K0: zero ACC/SUM/SQ/bitmap (replaces hipMemsetAsync dispatch) + block 0
// builds the 12 packed-bf16 B fragments (12KB).
// ---------------------------------------------------------------------------
__global__ __launch_bounds__(256) void prep_kernel(
    const float* __restrict__ w1, const float* __restrict__ seg_w,
    float* __restrict__ ws)
{
  // grid-stride zeroing, float4 (NZERO % 4 == 0)
  const int nvec = NZERO / 4;
  for (int i = blockIdx.x * 256 + threadIdx.x; i < nvec; i += gridDim.x * 256)
    ((float4*)ws)[i] = make_float4(0.f, 0.f, 0.f, 0.f);

  if (blockIdx.x == 0) {
    uint4* fr = (uint4*)(ws + OFF_FRAGS);
    for (int slot = threadIdx.x; slot < 768; slot += 256) {
      const int f = slot >> 6, l = slot & 63;
      const int col = l & 15, kg = l >> 4;
      const int t = f >> 1, ks = f & 1;
      union { uint4 q; unsigned short u[8]; } bu;
      #pragma unroll
      for (int i = 0; i < 8; ++i) {
        const int k = ks * 32 + kg * 8 + i;
        float v;
        if (t < 4)       v = w1[k * 64 + t * 16 + col];
        else if (t == 4) v = seg_w[k * 20 + col];
        else             v = (col < 4) ? seg_w[k * 20 + 16 + col] : 0.f;
        bu.u[i] = (unsigned short)bf16rne(v);
      }
      fr[slot] = bu.q;
    }
  }
}

// ---------------------------------------------------------------------------
// K1 (MFMA, barrier-free, depth-2 pipeline, assign fused at head):
// [h | seg logits] = feat@[w1|seg_w]; h u8, probs bf16 point-major.
// ---------------------------------------------------------------------------
__global__ __launch_bounds__(256) void gemm_kernel(
    const float* __restrict__ feat, const float* __restrict__ seg_b,
    const int* __restrict__ segment, const int* __restrict__ prop_ids,
    const int* __restrict__ point_ids, float* __restrict__ ws)
{
  float* acc   = ws + OFF_ACC;
  int*   segp  = (int*)(ws + OFF_SEGPRED);
  unsigned short* probs16 = (unsigned short*)(ws + OFF_PROBS);
  unsigned* h8 = (unsigned*)(ws + OFF_H);
  unsigned* bitmap = (unsigned*)(ws + OFF_BITMAP);

  const int tid  = threadIdx.x;
  const int lane = tid & 63;
  const int col  = lane & 15;
  const int kg   = lane >> 4;
  const int wslot0  = blockIdx.x * 4 + (tid >> 6);
  const int wstride = gridDim.x * 4;

  // ---- fused assign: scatter-or the dedupe bitmap (overlaps with frag loads)
  for (int i = blockIdx.x * 256 + tid; i < M_ASSIGN; i += 262144) {
    const int p = prop_ids[i];
    const int n = point_ids[i];
    atomicOr(&bitmap[p * WPR + (n >> 5)], 1u << (n & 31));
  }

  // ---- load prebuilt B fragments (12 coalesced 16B loads) ----
  const uint4* fr = (const uint4*)(ws + OFF_FRAGS);
  auto ldf = [&](int f) -> short8v {
    union { uint4 q; short8v v; } u;
    u.q = fr[f * 64 + lane];
    return u.v;
  };
  const short8v B00 = ldf(0),  B01 = ldf(1);
  const short8v B10 = ldf(2),  B11 = ldf(3);
  const short8v B20 = ldf(4),  B21 = ldf(5);
  const short8v B30 = ldf(6),  B31 = ldf(7);
  const short8v B40 = ldf(8),  B41 = ldf(9);
  const short8v B50 = ldf(10), B51 = ldf(11);

  const float sb4 = seg_b[col];
  const float sb5 = (col < 4) ? seg_b[16 + col] : 0.f;

  float bnsum[4] = {0.f, 0.f, 0.f, 0.f};
  float bnsq[4]  = {0.f, 0.f, 0.f, 0.f};
  float nll_acc = 0.f, vld_acc = 0.f;

  auto do_window = [&](int W, const short8v& A0v, const short8v& A1v) {
    f32x4 ac0 = {0.f,0.f,0.f,0.f}, ac1 = ac0, ac2 = ac0, ac3 = ac0;
    f32x4 ac4 = {sb4, sb4, sb4, sb4};
    f32x4 ac5 = {sb5, sb5, sb5, sb5};
    ac0 = __builtin_amdgcn_mfma_f32_16x16x32_bf16(A0v, B00, ac0, 0, 0, 0);
    ac0 = __builtin_amdgcn_mfma_f32_16x16x32_bf16(A1v, B01, ac0, 0, 0, 0);
    ac1 = __builtin_amdgcn_mfma_f32_16x16x32_bf16(A0v, B10, ac1, 0, 0, 0);
    ac1 = __builtin_amdgcn_mfma_f32_16x16x32_bf16(A1v, B11, ac1, 0, 0, 0);
    ac2 = __builtin_amdgcn_mfma_f32_16x16x32_bf16(A0v, B20, ac2, 0, 0, 0);
    ac2 = __builtin_amdgcn_mfma_f32_16x16x32_bf16(A1v, B21, ac2, 0, 0, 0);
    ac3 = __builtin_amdgcn_mfma_f32_16x16x32_bf16(A0v, B30, ac3, 0, 0, 0);
    ac3 = __builtin_amdgcn_mfma_f32_16x16x32_bf16(A1v, B31, ac3, 0, 0, 0);
    ac4 = __builtin_amdgcn_mfma_f32_16x16x32_bf16(A0v, B40, ac4, 0, 0, 0);
    ac4 = __builtin_amdgcn_mfma_f32_16x16x32_bf16(A1v, B41, ac4, 0, 0, 0);
    ac5 = __builtin_amdgcn_mfma_f32_16x16x32_bf16(A0v, B50, ac5, 0, 0, 0);
    ac5 = __builtin_amdgcn_mfma_f32_16x16x32_bf16(A1v, B51, ac5, 0, 0, 0);

    #pragma unroll
    for (int r = 0; r < 4; ++r) {
      bnsum[0] += ac0[r]; bnsq[0] += ac0[r] * ac0[r];
      bnsum[1] += ac1[r]; bnsq[1] += ac1[r] * ac1[r];
      bnsum[2] += ac2[r]; bnsq[2] += ac2[r] * ac2[r];
      bnsum[3] += ac3[r]; bnsq[3] += ac3[r] * ac3[r];
      h8[(size_t)(W * 4 + r) * 64 + lane] =
          q8(ac0[r]) | (q8(ac1[r]) << 8) | (q8(ac2[r]) << 16) | (q8(ac3[r]) << 24);

      const int p = W * 16 + kg * 4 + r;
      const int seg = segment[p];
      const float l4 = ac4[r];
      const float l5 = ac5[r];
      float mv; int mi;
      if (col < 4 && l5 > l4) { mv = l5; mi = 16 + col; }
      else                    { mv = l4; mi = col; }
      #pragma unroll
      for (int msk = 1; msk < 16; msk <<= 1) {
        const float om = __shfl_xor(mv, msk);
        const int   oi = __shfl_xor(mi, msk);
        if (om > mv || (om == mv && oi < mi)) { mv = om; mi = oi; }
      }
      const float e4 = __expf(l4 - mv);
      const float e5 = (col < 4) ? __expf(l5 - mv) : 0.f;
      const int sidx = seg < 0 ? 0 : (seg > 19 ? 19 : seg);
      float sp = e4 + e5;
      float lv = (col == sidx ? l4 : 0.f) + ((col < 4 && (16 + col) == sidx) ? l5 : 0.f);
      #pragma unroll
      for (int msk = 1; msk < 16; msk <<= 1) {
        sp += __shfl_xor(sp, msk);
        lv += __shfl_xor(lv, msk);
      }
      const float inv = 1.f / sp;
      probs16[(size_t)p * 20 + col] = (unsigned short)bf16rne(e4 * inv);
      if (col < 4) probs16[(size_t)p * 20 + 16 + col] = (unsigned short)bf16rne(e5 * inv);
      if (col == 0) {
        segp[p] = mi;
        const bool svalid = (seg != -1);
        nll_acc += svalid ? (mv + __logf(sp) - lv) : 0.f;
        vld_acc += svalid ? 1.f : 0.f;
      }
    }
  };

  auto loadA = [&](int W, f32x4& c0, f32x4& c1, f32x4& c2, f32x4& c3) {
    c0 = (f32x4){0.f,0.f,0.f,0.f}; c1 = c0; c2 = c0; c3 = c0;
    if (W < NWIN) {
      const float* fp = feat + (size_t)(W * 16 + col) * 64 + kg * 8;
      c0 = *(const f32x4*)(fp);
      c1 = *(const f32x4*)(fp + 4);
      c2 = *(const f32x4*)(fp + 32);
      c3 = *(const f32x4*)(fp + 36);
    }
  };
  auto cvtA = [&](const f32x4& c0, const f32x4& c1, const f32x4& c2, const f32x4& c3,
                  short8v& A0v, short8v& A1v) {
    union { short8v v; unsigned u[4]; } A0, A1;
    A0.u[0] = pk2(c0[0], c0[1]); A0.u[1] = pk2(c0[2], c0[3]);
    A0.u[2] = pk2(c1[0], c1[1]); A0.u[3] = pk2(c1[2], c1[3]);
    A1.u[0] = pk2(c2[0], c2[1]); A1.u[1] = pk2(c2[2], c2[3]);
    A1.u[2] = pk2(c3[0], c3[1]); A1.u[3] = pk2(c3[2], c3[3]);
    A0v = A0.v; A1v = A1.v;
  };

  // ---- depth-2 software pipeline ----
  f32x4 pa0, pa1, pa2, pa3, pb0, pb1, pb2, pb3;
  loadA(wslot0,            pa0, pa1, pa2, pa3);
  loadA(wslot0 + wstride,  pb0, pb1, pb2, pb3);

  for (int W = wslot0; W < NWIN; W += 2 * wstride) {
    {
      short8v A0v, A1v;
      cvtA(pa0, pa1, pa2, pa3, A0v, A1v);
      loadA(W + 2 * wstride, pa0, pa1, pa2, pa3);
      do_window(W, A0v, A1v);
    }
    const int W2 = W + wstride;
    if (W2 < NWIN) {
      short8v A0v, A1v;
      cvtA(pb0, pb1, pb2, pb3, A0v, A1v);
      loadA(W2 + 2 * wstride, pb0, pb1, pb2, pb3);
      do_window(W2, A0v, A1v);
    }
  }

  // ---- BN reduce ----
  #pragma unroll
  for (int t = 0; t < 4; ++t) {
    float s = bnsum[t], q = bnsq[t];
    s += __shfl_down(s, 32); s += __shfl_down(s, 16);
    q += __shfl_down(q, 32); q += __shfl_down(q, 16);
    if (lane < 16) {
      atomicAdd(&ws[OFF_SUM + t * 16 + lane], s);
      atomicAdd(&ws[OFF_SQ  + t * 16 + lane], q);
    }
  }
  float s = nll_acc, v = vld_acc;
  #pragma unroll
  for (int o = 32; o > 0; o >>= 1) { s += __shfl_down(s, o); v += __shfl_down(v, o); }
  if (lane == 0) { atomicAdd(&acc[0], s); atomicAdd(&acc[1], v); }
}

// ---------------------------------------------------------------------------
// K2 (merged): blocks [0,NBIAS) = bias-loss path (1024 thr, 1 point/thread);
// blocks [NBIAS, NBIAS+128) = per-proposal score path.
// ---------------------------------------------------------------------------
__global__ __launch_bounds__(1024) void biasscore_kernel(
    const float* __restrict__ coord, const float* __restrict__ cent,
    const float* __restrict__ gamma, const float* __restrict__ beta,
    const float* __restrict__ w2, const float* __restrict__ b2,
    const int* __restrict__ instance, const int* __restrict__ prop_ids,
    const int* __restrict__ point_ids, float* __restrict__ ws,
    float* __restrict__ out)
{
  const int tid = threadIdx.x;

  if (blockIdx.x < NBIAS) {
    // ================= bias-loss path =================
    __shared__ float scs[64], shs[64];
    __shared__ float r0[16], r1[16], r2[16];
    float* acc = ws + OFF_ACC;
    const unsigned* h8 = (const unsigned*)(ws + OFF_H);

    if (tid < 64) {
      const float mu  = ws[OFF_SUM + tid] * (1.f / NPTS);
      const float var = ws[OFF_SQ  + tid] * (1.f / NPTS) - mu * mu;
      const float sc = gamma[tid] * rsqrtf(var + 0.001f);
      scs[tid] = sc;
      shs[tid] = beta[tid] - mu * sc;   // b1 cancels through BN
    }
    __syncthreads();

    const int n = blockIdx.x * 1024 + tid;
    float l1v = 0.f, cosv = 0.f, mk = 0.f;
    if (n < NPTS) {
      const int W = n >> 4, q = n & 15, kg = (q >> 2) & 3, r = q & 3;
      const uint4* hp = (const uint4*)(h8 + ((size_t)(W * 4 + r) * 64 + kg * 16));
      uint4 u[4];
      #pragma unroll
      for (int i = 0; i < 4; ++i) u[i] = hp[i];

      float bx = b2[0], by = b2[1], bz = b2[2];
      #pragma unroll
      for (int i = 0; i < 4; ++i) {
        const unsigned uu[4] = {u[i].x, u[i].y, u[i].z, u[i].w};
        #pragma unroll
        for (int j = 0; j < 4; ++j) {
          const int cgi = i * 4 + j;
          const unsigned w = uu[j];
          #pragma unroll
          for (int b = 0; b < 4; ++b) {
            const int ch = cgi + 16 * b;
            const float h = (float)(int)((w >> (8 * b)) & 255u) * 0.0625f - 8.f;
            const float hr = fmaxf(fmaf(h, scs[ch], shs[ch]), 0.f);
            bx = fmaf(hr, w2[ch * 3 + 0], bx);
            by = fmaf(hr, w2[ch * 3 + 1], by);
            bz = fmaf(hr, w2[ch * 3 + 2], bz);
          }
        }
      }
      const float cx = coord[(size_t)n*3+0], cy = coord[(size_t)n*3+1], cz = coord[(size_t)n*3+2];
      const float ex = cent[(size_t)n*3+0],  ey = cent[(size_t)n*3+1],  ez = cent[(size_t)n*3+2];
      const float gx = ex - cx, gy = ey - cy, gz = ez - cz;
      const float dx = bx - gx, dy = by - gy, dz = bz - gz;
      const float l1 = fabsf(dx) + fabsf(dy) + fabsf(dz);
      const float npn = sqrtf(bx*bx + by*by + bz*bz) + 1e-8f;
      const float ngn = sqrtf(gx*gx + gy*gy + gz*gz) + 1e-8f;
      const float cv = -(bx*gx + by*gy + bz*gz) / (npn * ngn);
      mk = (instance[n] != -1) ? 1.f : 0.f;
      l1v = l1 * mk;
      cosv = cv * mk;
    }
    #pragma unroll
    for (int o = 32; o > 0; o >>= 1) {
      l1v  += __shfl_down(l1v, o);
      cosv += __shfl_down(cosv, o);
      mk   += __shfl_down(mk, o);
    }
    if ((tid & 63) == 0) { r0[tid>>6] = l1v; r1[tid>>6] = cosv; r2[tid>>6] = mk; }
    __syncthreads();
    if (tid == 0) {
      float a = 0.f, b = 0.f, c = 0.f;
      #pragma unroll
      for (int i = 0; i < 16; ++i) { a += r0[i]; b += r1[i]; c += r2[i]; }
      atomicAdd(&acc[2], a);
      atomicAdd(&acc[3], b);
      atomicAdd(&acc[4], c);
    }
  } else {
    // ================= score path =================
    const unsigned* bitmap = (const unsigned*)(ws + OFF_BITMAP);
    const unsigned short* probs16 = (const unsigned short*)(ws + OFF_PROBS);
    const int* segp = (const int*)(ws + OFF_SEGPRED);
    __shared__ float rs[16];
    __shared__ int rc[16];
    const int p = blockIdx.x - NBIAS;

    int lo = 0, hi = M_ASSIGN;
    while (lo < hi) { const int mid = (lo + hi) >> 1; if (prop_ids[mid] < p) lo = mid + 1; else hi = mid; }
    if (lo > M_ASSIGN - 1) lo = M_ASSIGN - 1;
    const int cp = segp[point_ids[lo]];

    float s = 0.f; int cnt = 0;
    for (int w = tid; w < WPR; w += 1024) {
      unsigned bits = bitmap[p * WPR + w];
      cnt += __popc(bits);
      while (bits) {
        const int b = __ffs(bits) - 1;
        bits &= bits - 1;
        const int n = (w << 5) + b;
        s += __uint_as_float((unsigned)probs16[(size_t)n * 20 + cp] << 16);
      }
    }
    #pragma unroll
    for (int o = 32; o > 0; o >>= 1) { s += __shfl_down(s, o); cnt += __shfl_down(cnt, o); }
    if ((tid & 63) == 0) { rs[tid >> 6] = s; rc[tid >> 6] = cnt; }
    __syncthreads();
    if (tid == 0) {
      float st = 0.f; int ct = 0;
      #pragma unroll
      for (int i = 0; i < 16; ++i) { st += rs[i]; ct += rc[i]; }
      const bool mk = ct > 100;
      out[1 + p]   = mk ? st / (float)(ct > 1 ? ct : 1) : 0.f;
      out[129 + p] = mk ? 1.f : 0.f;
      if (p == 0) {
        const float segl = ws[0] / fmaxf(ws[1], 1.f);
        const float d = ws[4] + 1e-8f;
        out[0] = segl + ws[2] / d + ws[3] / d;
      }
    }
  }
}

extern "C" void kernel_launch(void* const* d_in, const int* in_sizes, int n_in,
                              void* d_out, int out_size, void* d_ws, size_t ws_size,
                              hipStream_t stream) {
  const float* feat    = (const float*)d_in[0];
  const float* coord   = (const float*)d_in[1];
  const float* cent    = (const float*)d_in[2];
  const float* w1      = (const float*)d_in[3];
  // d_in[4] = b1 : cancels through BN, unused
  const float* gamma   = (const float*)d_in[5];
  const float* beta    = (const float*)d_in[6];
  const float* w2      = (const float*)d_in[7];
  const float* b2      = (const float*)d_in[8];
  const float* seg_w   = (const float*)d_in[9];
  const float* seg_b   = (const float*)d_in[10];
  const int* segment   = (const int*)d_in[11];
  const int* instance  = (const int*)d_in[12];
  const int* prop_ids  = (const int*)d_in[13];
  const int* point_ids = (const int*)d_in[14];
  float* out = (float*)d_out;
  float* ws  = (float*)d_ws;

  prep_kernel<<<1024, 256, 0, stream>>>(w1, seg_w, ws);
  gemm_kernel<<<1024, 256, 0, stream>>>(feat, seg_b, segment, prop_ids, point_ids, ws);
  biasscore_kernel<<<NBIAS + 128, 1024, 0, stream>>>(coord, cent, gamma, beta, w2, b2,
                                                     instance, prop_ids, point_ids, ws, out);
}